// Round 20
// baseline (62.454 us; speedup 1.0000x reference)
//
#include <hip/hip_runtime.h>
#include <hip/hip_bf16.h>

// Problem constants (fixed by the reference)
#define Bz 8
#define Cc 256
#define HWp 23104            // 152*152
#define Kk 1024
#define BK (Bz*Kk)
#define MARGIN_F 10.0f
#define BIGF 1e30f
#define TILE 128
#define NBK 128              // buckets (hw>>8 in [0,90], padded to 128)

typedef __attribute__((ext_vector_type(8))) short bf16x8;  // 8 bf16 = 4 VGPRs
typedef __attribute__((ext_vector_type(4))) float f32x4;   // MFMA 16x16 accumulator

// ---------------------------------------------------------------------------
// K0: per-batch BUCKET sort with parallel Hillis-Steele prefix (verbatim
// R18, proven).  Intra-bucket order is timing-dependent but every downstream
// output byte is order-independent.  Inits neg_min + acc + cntRG[64] + cnt2
// (ws poisoned once; counters end each launch nonzero and are re-zeroed
// here -> graph-replay safe; kernel-boundary ordering makes them visible).
// ---------------------------------------------------------------------------
__global__ __launch_bounds__(1024) void bucket_sort(
    const int* __restrict__ ind, uint* __restrict__ sorted,
    unsigned* __restrict__ neg, float* __restrict__ acc,
    unsigned* __restrict__ cntRG, unsigned* __restrict__ cnt2)
{
    __shared__ uint cur[NBK], pre[NBK];
    const int b = blockIdx.x, tid = threadIdx.x;
    if (tid < NBK) cur[tid] = 0;
    neg[b * Kk + tid] = __float_as_uint(BIGF);
    if (b == 0) {
        if (tid < 64) cntRG[tid] = 0u;
        if (tid == 64) *cnt2 = 0u;
        if (tid == 65 || tid == 66) acc[tid - 65] = 0.f;
    }
    __syncthreads();
    int hw = ind[b * Kk + tid];
    int bk = hw >> 8;                       // 0..90
    atomicAdd(&cur[bk], 1u);
    __syncthreads();
    uint mycount = (tid < NBK) ? cur[tid] : 0u;
    if (tid < NBK) pre[tid] = mycount;
    __syncthreads();
    #pragma unroll
    for (int off = 1; off < NBK; off <<= 1) {   // inclusive scan, 7 steps
        uint add = (tid < NBK && tid >= off) ? pre[tid - off] : 0u;
        __syncthreads();
        if (tid < NBK) pre[tid] += add;
        __syncthreads();
    }
    if (tid < NBK) cur[tid] = pre[tid] - mycount;   // exclusive cursor
    __syncthreads();
    uint slot = atomicAdd(&cur[bk], 1u);    // unique slot within bucket
    sorted[b * Kk + slot] = ((uint)hw << 10) | (uint)tid;
}

// ---------------------------------------------------------------------------
// K1: sorted gather + fused ssq partials (VERBATIM R17/R18, proven).
// Thread t: entry kl = t>>2, octet cq = t&3; 8 independent loads/thread;
// 2x shfl_xor -> 32-channel ssq partial; cq==0 stores ssq_part[cg][row].
// embr writes: ONE full 64B line per k, exactly once.
// ---------------------------------------------------------------------------
__global__ __launch_bounds__(256) void sorted_gather(
    const float* __restrict__ x, const uint* __restrict__ sorted,
    __hip_bfloat16* __restrict__ embr, float* __restrict__ ssq_part)
{
    const int kq = blockIdx.x, cg = blockIdx.y, b = blockIdx.z;
    const int c0 = cg * 32;
    const int t = threadIdx.x;
    const int kl = t >> 2, cq = t & 3;
    uint e = sorted[b * Kk + kq * 64 + kl];
    int hw = (int)(e >> 10), k = (int)(e & 1023u);
    const float* xp = x + (size_t)(b * Cc + c0 + cq * 8) * HWp + hw;
    float v[8];
    #pragma unroll
    for (int j = 0; j < 8; ++j) v[j] = xp[(size_t)j * HWp];

    ushort ev[8]; float s2 = 0.f;
    #pragma unroll
    for (int j = 0; j < 8; ++j) {
        ev[j] = __hip_bfloat16_raw(__float2bfloat16(v[j])).x;
        float f = __uint_as_float((uint)ev[j] << 16);
        s2 += f * f;
    }
    s2 += __shfl_xor(s2, 1);
    s2 += __shfl_xor(s2, 2);                // sum over the 4 cq-lanes

    uint4 o = make_uint4((uint)ev[0] | ((uint)ev[1] << 16),
                         (uint)ev[2] | ((uint)ev[3] << 16),
                         (uint)ev[4] | ((uint)ev[5] << 16),
                         (uint)ev[6] | ((uint)ev[7] << 16));
    *(uint4*)((ushort*)embr + (size_t)(b * Kk + k) * Cc + c0 + cq * 8) = o;
    if (cq == 0)
        ssq_part[cg * BK + b * Kk + k] = s2;
}

// ---------------------------------------------------------------------------
// K2: Gram + scl preamble (verbatim R17/R18 core) + ABSORBED hinge via a
// per-rowgroup elected tail.  Each (b, iy) rowgroup of 128 rows receives
// atomicMins from exactly 8 blocks (jx=0..7).  Each block: threadfence +
// ACQ_REL fetch_add on cntRG[b*8+iy]; the block seeing prev==7 reads its
// 128 neg values via agent-scope atomic loads (~1us; 64x below the R10/R15
// single-block-8192 poison), computes hinge partials, 2 atomicAdds into
// acc, and a second 64-wide election writes out from 2 coherent RMWs.
// This is the R18-proven tail pattern, scaled 32->64 electors; removes the
// hinge kernel + one dispatch boundary.
// d2 = 200 - 2*scl_i*scl_j*Graw, clamped >= 0 BEFORE the uint-bit atomicMin
// (duplicate-index pairs = the loss signal; identical rows -> identical scl).
// ---------------------------------------------------------------------------
__global__ __launch_bounds__(256) void gram_min_hinge(
    const __hip_bfloat16* __restrict__ emb, const float* __restrict__ ssq_part,
    const int* __restrict__ mask, unsigned* __restrict__ neg,
    float* __restrict__ acc, unsigned* __restrict__ cntRG,
    unsigned* __restrict__ cnt2, float* __restrict__ out)
{
    __shared__ __align__(16) short As[TILE * 64];   // 16 KB
    __shared__ __align__(16) short Bs[TILE * 64];   // 16 KB
    __shared__ float scl_i[TILE], scl_j[TILE];      // 1 KB
    __shared__ float redh[4], redv[4];
    __shared__ uint lastFlag;

    int b  = blockIdx.z;
    int i0 = blockIdx.y * TILE;
    int j0 = blockIdx.x * TILE;
    int tid = threadIdx.x;
    int w  = tid >> 6, l = tid & 63;
    int wr = w >> 1, wc = w & 1;          // wave's 64x64 quadrant
    int lr = l & 15, lg = l >> 4;         // lane row / k-group

    // ---- preamble: scl for the block's 128 i-rows and 128 j-rows ---------
    {
        int m  = tid >> 7;                 // 0 = i-panel, 1 = j-panel
        int rl = tid & 127;
        int grow = b * Kk + (m ? j0 : i0) + rl;
        float s2 = 0.f;
        #pragma unroll
        for (int c = 0; c < 8; ++c) s2 += ssq_part[c * BK + grow];
        float sc = 10.0f / fmaxf(sqrtf(s2), 1e-12f);
        if (m) scl_j[rl] = sc; else scl_i[rl] = sc;
    }
    // (first k-loop __syncthreads orders these writes before epilogue reads)

    const short* E  = (const short*)emb + (size_t)b * Kk * Cc;
    const short* EA = E + (size_t)i0 * Cc;
    const short* EB = E + (size_t)j0 * Cc;

    // staging: instr t (=w*4+q) fills LDS rows t*8..t*8+7; lane l ->
    // row offset l/8, slot l%8; source k-chunk = (l%8) ^ (l/8).
    const int lrow = l >> 3;
    const int lsub = (l & 7) ^ lrow;

    f32x4 accf[4][4] = {};
    for (int k0 = 0; k0 < Cc; k0 += 64) {
        #pragma unroll
        for (int q = 0; q < 4; ++q) {
            int t = w * 4 + q;
            int r = t * 8 + lrow;
            __builtin_amdgcn_global_load_lds(
                (const __attribute__((address_space(1))) void*)(EA + (size_t)r * Cc + k0 + lsub * 8),
                (__attribute__((address_space(3))) void*)&As[t * 512], 16, 0, 0);
            __builtin_amdgcn_global_load_lds(
                (const __attribute__((address_space(1))) void*)(EB + (size_t)r * Cc + k0 + lsub * 8),
                (__attribute__((address_space(3))) void*)&Bs[t * 512], 16, 0, 0);
        }
        __syncthreads();

        #pragma unroll
        for (int kk = 0; kk < 2; ++kk) {
            bf16x8 af[4], bf[4];
            #pragma unroll
            for (int f = 0; f < 4; ++f) {
                int ra = wr * 64 + f * 16 + lr;
                af[f] = *(const bf16x8*)&As[ra * 64 + (((kk * 4 + lg) ^ (ra & 7)) << 3)];
                int rb = wc * 64 + f * 16 + lr;
                bf[f] = *(const bf16x8*)&Bs[rb * 64 + (((kk * 4 + lg) ^ (rb & 7)) << 3)];
            }
            #pragma unroll
            for (int fi = 0; fi < 4; ++fi)
                #pragma unroll
                for (int fj = 0; fj < 4; ++fj)
                    accf[fi][fj] = __builtin_amdgcn_mfma_f32_16x16x32_bf16(
                                      af[fi], bf[fj], accf[fi][fj], 0, 0, 0);
        }
        __syncthreads();
    }

    const int* mb = mask + b * Kk;
    float cjv[4]; int jgv[4]; bool jva[4];
    #pragma unroll
    for (int fj = 0; fj < 4; ++fj) {
        int jl = wc * 64 + fj * 16 + lr;
        jgv[fj] = j0 + jl;
        cjv[fj] = scl_j[jl];
        jva[fj] = (mb[j0 + jl] != 0);
    }
    #pragma unroll
    for (int fi = 0; fi < 4; ++fi) {
        #pragma unroll
        for (int r = 0; r < 4; ++r) {
            int il = wr * 64 + fi * 16 + 4 * lg + r;
            int ig = i0 + il;
            float ci = scl_i[il];
            float m = BIGF;
            #pragma unroll
            for (int fj = 0; fj < 4; ++fj) {
                float d2 = fmaxf(200.0f - 2.0f * ci * cjv[fj] * accf[fi][fj][r], 0.0f);
                bool ok = jva[fj] && (jgv[fj] != ig);
                m = ok ? fminf(m, d2) : m;
            }
            #pragma unroll
            for (int off = 1; off < 16; off <<= 1)
                m = fminf(m, __shfl_xor(m, off));
            if (lr == 0)
                atomicMin(&neg[b * Kk + ig], __float_as_uint(m));
        }
    }

    // ---- per-rowgroup elected hinge tail ----------------------------------
    __syncthreads();                        // all threads' atomicMins issued
    if (tid == 0) {
        __threadfence();                    // release this block's mins
        unsigned prev = __hip_atomic_fetch_add(&cntRG[b * 8 + blockIdx.y], 1u,
                                               __ATOMIC_ACQ_REL,
                                               __HIP_MEMORY_SCOPE_AGENT);
        lastFlag = (prev == 7u) ? 1u : 0u;
    }
    __syncthreads();
    if (lastFlag) {
        float h = 0.f, v = 0.f;
        if (tid < TILE) {
            unsigned nb = __hip_atomic_load(&neg[b * Kk + i0 + tid],
                                            __ATOMIC_RELAXED,
                                            __HIP_MEMORY_SCOPE_AGENT);
            if (mb[i0 + tid] != 0) {
                float d = sqrtf(__uint_as_float(nb));
                h = fmaxf(MARGIN_F - d, 0.f);
                v = 1.f;
            }
        }
        #pragma unroll
        for (int off = 1; off < 64; off <<= 1) {
            h += __shfl_xor(h, off);
            v += __shfl_xor(v, off);
        }
        if (l == 0) { redh[w] = h; redv[w] = v; }
        __syncthreads();
        if (tid == 0) {
            atomicAdd(&acc[0], redh[0] + redh[1] + redh[2] + redh[3]);
            atomicAdd(&acc[1], redv[0] + redv[1] + redv[2] + redv[3]);
            __threadfence();
            unsigned p2 = __hip_atomic_fetch_add(cnt2, 1u, __ATOMIC_ACQ_REL,
                                                 __HIP_MEMORY_SCOPE_AGENT);
            if (p2 == 63u) {
                float H = atomicAdd(&acc[0], 0.0f);   // 2 coherent RMW reads
                float V = atomicAdd(&acc[1], 0.0f);
                out[0] = H / V;
            }
        }
    }
}

// ---------------------------------------------------------------------------
extern "C" void kernel_launch(void* const* d_in, const int* in_sizes, int n_in,
                              void* d_out, int out_size, void* d_ws, size_t ws_size,
                              hipStream_t stream) {
    const float* x    = (const float*)d_in[0];   // [B,C,H,W] fp32
    const int*   ind  = (const int*)d_in[1];     // [B,K] int32
    const int*   mask = (const int*)d_in[2];     // [B,K] int32
    float* out = (float*)d_out;

    // ws layout: embr bf16 [B*K][C] (4 MB) | ssq_part f32 [8][B*K] (256 KB)
    //            | neg u32 [B*K] | sorted u32 [B*K] | acc f32[2]
    //            | cntRG u32[64] | cnt2 u32
    __hip_bfloat16* embr = (__hip_bfloat16*)d_ws;
    float*    ssq_part = (float*)((char*)d_ws + (size_t)BK * Cc * sizeof(__hip_bfloat16));
    unsigned* neg    = (unsigned*)(ssq_part + 8 * BK);
    uint*     sorted = (uint*)(neg + BK);
    float*    acc    = (float*)(sorted + BK);
    unsigned* cntRG  = (unsigned*)(acc + 2);
    unsigned* cnt2   = cntRG + 64;

    bucket_sort<<<Bz, 1024, 0, stream>>>(ind, sorted, neg, acc, cntRG, cnt2);
    dim3 g1(16, Cc / 32, Bz);                 // (16 kq, 8 cgroups, 8 b)
    sorted_gather<<<g1, 256, 0, stream>>>(x, sorted, embr, ssq_part);
    dim3 g2(Kk / TILE, Kk / TILE, Bz);        // 512 blocks
    gram_min_hinge<<<g2, 256, 0, stream>>>(embr, ssq_part, mask, neg,
                                           acc, cntRG, cnt2, out);
}

// Round 21
// 46.753 us; speedup vs baseline: 1.3358x; 1.3358x over previous
//
#include <hip/hip_runtime.h>
#include <hip/hip_bf16.h>

// Problem constants (fixed by the reference)
#define Bz 8
#define Cc 256
#define HWp 23104            // 152*152 = 16 ranges * 1444
#define RNG 1444             // positions per hw-range
#define Kk 1024
#define BK (Bz*Kk)
#define MARGIN_F 10.0f
#define BIGF 1e30f
#define TILE 128

typedef __attribute__((ext_vector_type(8))) short bf16x8;  // 8 bf16 = 4 VGPRs
typedef __attribute__((ext_vector_type(4))) float f32x4;   // MFMA 16x16 accumulator

// ---------------------------------------------------------------------------
// K0: filter-gather + fused ssq partials.  R19 lesson: in-kernel elected
// tails/fences = +13..30us; R17 lesson: cheap redundant recompute in the
// consumer is free.  So the bucket sort moves INTO the gather: each block
// (range, cg, b) reads ind[b] (4 KB coalesced, L2-resident after first
// touch), filters to its 1444-position hw-range, LDS-compacts (~64 entries,
// cursor atomicAdd -- order timing-dependent but output-irrelevant: each k
// writes only its own embr row, value = f(k, ind[k])).  Then the VERBATIM
// R13/R18 gather body: thread t -> entry e = t>>2 (+64/iter), octet cq=t&3,
// 8 independent loads, 2x shfl_xor ssq partial, ONE full 64B embr line per
// (k, cgroup), exactly once.  Kills the sort kernel + boundary + sorted[].
// Blocks (range==0, cg==0) also init neg/acc/cnt (ws poisoned once only;
// kernel boundary orders inits before gram).
// ---------------------------------------------------------------------------
__global__ __launch_bounds__(256) void filter_gather(
    const float* __restrict__ x, const int* __restrict__ ind,
    __hip_bfloat16* __restrict__ embr, float* __restrict__ ssq_part,
    unsigned* __restrict__ neg, float* __restrict__ acc,
    unsigned* __restrict__ cnt)
{
    __shared__ uint lst[Kk];                // 4 KB: worst-case capacity
    __shared__ uint lcnt;
    const int rg = blockIdx.x, cg = blockIdx.y, b = blockIdx.z;
    const int c0 = cg * 32;
    const int t  = threadIdx.x;
    const int lo = rg * RNG;

    if (t == 0) lcnt = 0u;
    if (rg == 0 && cg == 0) {               // one block per b does inits
        #pragma unroll
        for (int q = 0; q < 4; ++q)
            neg[b * Kk + q * 256 + t] = __float_as_uint(BIGF);
        if (b == 0 && t < 2) acc[t] = 0.f;
        if (b == 0 && t == 2) *cnt = 0u;
    }
    __syncthreads();

    const int* indb = ind + b * Kk;
    #pragma unroll
    for (int q = 0; q < 4; ++q) {
        int k  = q * 256 + t;
        int hw = indb[k];
        unsigned off = (unsigned)(hw - lo);
        if (off < (unsigned)RNG) {
            uint slot = atomicAdd(&lcnt, 1u);
            lst[slot] = ((uint)hw << 10) | (uint)k;
        }
    }
    __syncthreads();
    const int n = (int)lcnt;

    const int cq = t & 3;
    for (int e = t >> 2; e < n; e += 64) {
        uint ent = lst[e];
        int hw = (int)(ent >> 10), k = (int)(ent & 1023u);
        const float* xp = x + (size_t)(b * Cc + c0 + cq * 8) * HWp + hw;
        float v[8];
        #pragma unroll
        for (int j = 0; j < 8; ++j) v[j] = xp[(size_t)j * HWp];

        ushort ev[8]; float s2 = 0.f;
        #pragma unroll
        for (int j = 0; j < 8; ++j) {
            ev[j] = __hip_bfloat16_raw(__float2bfloat16(v[j])).x;
            float f = __uint_as_float((uint)ev[j] << 16);
            s2 += f * f;
        }
        s2 += __shfl_xor(s2, 1);
        s2 += __shfl_xor(s2, 2);            // sum over the 4 cq-lanes

        uint4 o = make_uint4((uint)ev[0] | ((uint)ev[1] << 16),
                             (uint)ev[2] | ((uint)ev[3] << 16),
                             (uint)ev[4] | ((uint)ev[5] << 16),
                             (uint)ev[6] | ((uint)ev[7] << 16));
        *(uint4*)((ushort*)embr + (size_t)(b * Kk + k) * Cc + c0 + cq * 8) = o;
        if (cq == 0)
            ssq_part[cg * BK + b * Kk + k] = s2;
    }
}

// ---------------------------------------------------------------------------
// K1: Gram + scl preamble from ssq partials (VERBATIM R17/R18, proven).
// d2 = 200 - 2*scl_i*scl_j*Graw, clamped >= 0 BEFORE the uint-bit atomicMin
// (duplicate-index pairs = the loss signal; identical rows -> identical scl).
// ---------------------------------------------------------------------------
__global__ __launch_bounds__(256) void gram_mfma_min(
    const __hip_bfloat16* __restrict__ emb, const float* __restrict__ ssq_part,
    const int* __restrict__ mask, unsigned* __restrict__ neg)
{
    __shared__ __align__(16) short As[TILE * 64];   // 16 KB
    __shared__ __align__(16) short Bs[TILE * 64];   // 16 KB
    __shared__ float scl_i[TILE], scl_j[TILE];      // 1 KB
    int b  = blockIdx.z;
    int i0 = blockIdx.y * TILE;
    int j0 = blockIdx.x * TILE;
    int tid = threadIdx.x;
    int w  = tid >> 6, l = tid & 63;
    int wr = w >> 1, wc = w & 1;          // wave's 64x64 quadrant
    int lr = l & 15, lg = l >> 4;         // lane row / k-group

    // ---- preamble: scl for the block's 128 i-rows and 128 j-rows ---------
    {
        int m  = tid >> 7;                 // 0 = i-panel, 1 = j-panel
        int rl = tid & 127;
        int grow = b * Kk + (m ? j0 : i0) + rl;
        float s2 = 0.f;
        #pragma unroll
        for (int c = 0; c < 8; ++c) s2 += ssq_part[c * BK + grow];
        float sc = 10.0f / fmaxf(sqrtf(s2), 1e-12f);
        if (m) scl_j[rl] = sc; else scl_i[rl] = sc;
    }
    // (first k-loop __syncthreads orders these writes before epilogue reads)

    const short* E  = (const short*)emb + (size_t)b * Kk * Cc;
    const short* EA = E + (size_t)i0 * Cc;
    const short* EB = E + (size_t)j0 * Cc;

    // staging: instr t (=w*4+q) fills LDS rows t*8..t*8+7; lane l ->
    // row offset l/8, slot l%8; source k-chunk = (l%8) ^ (l/8).
    const int lrow = l >> 3;
    const int lsub = (l & 7) ^ lrow;

    f32x4 acc[4][4] = {};
    for (int k0 = 0; k0 < Cc; k0 += 64) {
        #pragma unroll
        for (int q = 0; q < 4; ++q) {
            int t = w * 4 + q;
            int r = t * 8 + lrow;
            __builtin_amdgcn_global_load_lds(
                (const __attribute__((address_space(1))) void*)(EA + (size_t)r * Cc + k0 + lsub * 8),
                (__attribute__((address_space(3))) void*)&As[t * 512], 16, 0, 0);
            __builtin_amdgcn_global_load_lds(
                (const __attribute__((address_space(1))) void*)(EB + (size_t)r * Cc + k0 + lsub * 8),
                (__attribute__((address_space(3))) void*)&Bs[t * 512], 16, 0, 0);
        }
        __syncthreads();

        #pragma unroll
        for (int kk = 0; kk < 2; ++kk) {
            bf16x8 af[4], bf[4];
            #pragma unroll
            for (int f = 0; f < 4; ++f) {
                int ra = wr * 64 + f * 16 + lr;
                af[f] = *(const bf16x8*)&As[ra * 64 + (((kk * 4 + lg) ^ (ra & 7)) << 3)];
                int rb = wc * 64 + f * 16 + lr;
                bf[f] = *(const bf16x8*)&Bs[rb * 64 + (((kk * 4 + lg) ^ (rb & 7)) << 3)];
            }
            #pragma unroll
            for (int fi = 0; fi < 4; ++fi)
                #pragma unroll
                for (int fj = 0; fj < 4; ++fj)
                    acc[fi][fj] = __builtin_amdgcn_mfma_f32_16x16x32_bf16(
                                      af[fi], bf[fj], acc[fi][fj], 0, 0, 0);
        }
        __syncthreads();
    }

    const int* mb = mask + b * Kk;
    float cjv[4]; int jgv[4]; bool jva[4];
    #pragma unroll
    for (int fj = 0; fj < 4; ++fj) {
        int jl = wc * 64 + fj * 16 + lr;
        jgv[fj] = j0 + jl;
        cjv[fj] = scl_j[jl];
        jva[fj] = (mb[j0 + jl] != 0);
    }
    #pragma unroll
    for (int fi = 0; fi < 4; ++fi) {
        #pragma unroll
        for (int r = 0; r < 4; ++r) {
            int il = wr * 64 + fi * 16 + 4 * lg + r;
            int ig = i0 + il;
            float ci = scl_i[il];
            float m = BIGF;
            #pragma unroll
            for (int fj = 0; fj < 4; ++fj) {
                float d2 = fmaxf(200.0f - 2.0f * ci * cjv[fj] * acc[fi][fj][r], 0.0f);
                bool ok = jva[fj] && (jgv[fj] != ig);
                m = ok ? fminf(m, d2) : m;
            }
            #pragma unroll
            for (int off = 1; off < 16; off <<= 1)
                m = fminf(m, __shfl_xor(m, off));
            if (lr == 0)
                atomicMin(&neg[b * Kk + ig], __float_as_uint(m));
        }
    }
}

// ---------------------------------------------------------------------------
// K2: hinge + mean, distributed (VERBATIM R18, proven): 32 blocks x 256
// threads, per-block atomicAdd into acc[2], elected-last via acq_rel
// fetch_add on cnt (32 fences in a TINY kernel = free, unlike in-gram);
// winner reads exactly 2 coherent RMWs and writes out.
// ---------------------------------------------------------------------------
__global__ __launch_bounds__(256) void hinge_final(
    const unsigned* __restrict__ neg, const int* __restrict__ mask,
    float* __restrict__ acc, unsigned* __restrict__ cnt,
    float* __restrict__ out)
{
    const int tid = threadIdx.x;
    const int i = blockIdx.x * 256 + tid;
    float h = 0.f, v = 0.f;
    if (mask[i] != 0) {
        float d = sqrtf(__uint_as_float(neg[i]));
        h = fmaxf(MARGIN_F - d, 0.f);
        v = 1.f;
    }
    #pragma unroll
    for (int off = 32; off; off >>= 1) {
        h += __shfl_xor(h, off);
        v += __shfl_xor(v, off);
    }
    __shared__ float sh[4], sv[4];
    int w = tid >> 6;
    if ((tid & 63) == 0) { sh[w] = h; sv[w] = v; }
    __syncthreads();
    if (tid == 0) {
        atomicAdd(&acc[0], sh[0] + sh[1] + sh[2] + sh[3]);
        atomicAdd(&acc[1], sv[0] + sv[1] + sv[2] + sv[3]);
        unsigned prev = __hip_atomic_fetch_add(cnt, 1u, __ATOMIC_ACQ_REL,
                                               __HIP_MEMORY_SCOPE_AGENT);
        if (prev == 31u) {
            float H = atomicAdd(&acc[0], 0.0f);   // coherent RMW reads (2)
            float V = atomicAdd(&acc[1], 0.0f);
            out[0] = H / V;
        }
    }
}

// ---------------------------------------------------------------------------
extern "C" void kernel_launch(void* const* d_in, const int* in_sizes, int n_in,
                              void* d_out, int out_size, void* d_ws, size_t ws_size,
                              hipStream_t stream) {
    const float* x    = (const float*)d_in[0];   // [B,C,H,W] fp32
    const int*   ind  = (const int*)d_in[1];     // [B,K] int32
    const int*   mask = (const int*)d_in[2];     // [B,K] int32
    float* out = (float*)d_out;

    // ws layout: embr bf16 [B*K][C] (4 MB) | ssq_part f32 [8][B*K] (256 KB)
    //            | neg u32 [B*K] | acc f32[2] | cnt u32
    __hip_bfloat16* embr = (__hip_bfloat16*)d_ws;
    float*    ssq_part = (float*)((char*)d_ws + (size_t)BK * Cc * sizeof(__hip_bfloat16));
    unsigned* neg = (unsigned*)(ssq_part + 8 * BK);
    float*    acc = (float*)(neg + BK);
    unsigned* cnt = (unsigned*)(acc + 2);

    dim3 g0(HWp / RNG, Cc / 32, Bz);          // (16 ranges, 8 cgroups, 8 b)
    filter_gather<<<g0, 256, 0, stream>>>(x, ind, embr, ssq_part, neg, acc, cnt);
    dim3 g1(Kk / TILE, Kk / TILE, Bz);
    gram_mfma_min<<<g1, 256, 0, stream>>>(embr, ssq_part, mask, neg);
    hinge_final<<<32, 256, 0, stream>>>(neg, mask, acc, cnt, out);
}